// Round 3
// baseline (327.911 us; speedup 1.0000x reference)
//
#include <hip/hip_runtime.h>

typedef __attribute__((ext_vector_type(8))) short short8;
typedef __attribute__((ext_vector_type(4))) float f32x4;

#define DEVI static __device__ __forceinline__

constexpr int NB   = 4;     // batch
constexpr int NH   = 2;     // heads
constexpr int SEQ  = 2048;  // Lq = Lk
constexpr int DM   = 512;   // d_model
constexpr int DKV  = 64;    // d_k = d_v
constexpr int HDIM = 128;   // NH * DKV

DEVI unsigned short f2bf(float f) {
    union { float f; unsigned u; } v; v.f = f;
    unsigned r = v.u + 0x7FFFu + ((v.u >> 16) & 1u);
    return (unsigned short)(r >> 16);
}
DEVI float bf2f(unsigned short s) {
    union { unsigned u; float f; } v; v.u = ((unsigned)s) << 16; return v.f;
}
DEVI unsigned pk2(float a, float b) {
    return (unsigned)f2bf(a) | ((unsigned)f2bf(b) << 16);
}
// async global->LDS, 16B per lane. LDS dest = wave-uniform base + lane*16.
DEVI void async16(const void* g, void* l) {
    __builtin_amdgcn_global_load_lds(
        (const __attribute__((address_space(1))) unsigned int*)g,
        (__attribute__((address_space(3))) unsigned int*)l, 16, 0, 0);
}

// ---------------------------------------------------------------------------
// k_prep: weights f32 -> bf16, transposed so MFMA B-operand rows are K-contig.
__global__ __launch_bounds__(256) void k_prep(
    const float* __restrict__ Wq, const float* __restrict__ Wk,
    const float* __restrict__ Wv, const float* __restrict__ Wo,
    unsigned short* __restrict__ Wqt, unsigned short* __restrict__ Wkt,
    unsigned short* __restrict__ Wvt, unsigned short* __restrict__ Wot) {
    int id = blockIdx.x * 256 + threadIdx.x;        // 0 .. 262143
    int which = id >> 16;
    int rem = id & 65535;
    if (which < 3) {
        const float* W = which == 0 ? Wq : (which == 1 ? Wk : Wv);
        unsigned short* Wt = which == 0 ? Wqt : (which == 1 ? Wkt : Wvt);
        int n = rem >> 9, k = rem & 511;            // dst [128][512]
        Wt[rem] = f2bf(W[k * HDIM + n]);
    } else {
        int n = rem >> 7, k = rem & 127;            // dst [512][128]
        Wot[rem] = f2bf(Wo[k * DM + n]);
    }
}

// ---------------------------------------------------------------------------
// k_proj: X[8192,512] @ W[512,128] + b  ->  per-head bf16 layouts.
// Double-buffered LDS (lA 2x4KB, lB 2x16KB = 40KB -> 4 blocks/CU), X loads
// issued one K-step early, W async16 one step ahead, ONE barrier per K-step.
__global__ __launch_bounds__(256) void k_proj(
    const float* __restrict__ Qg, const float* __restrict__ Kg, const float* __restrict__ Vg,
    const unsigned short* __restrict__ Wqt, const unsigned short* __restrict__ Wkt,
    const unsigned short* __restrict__ Wvt,
    const float* __restrict__ bq, const float* __restrict__ bk, const float* __restrict__ bv,
    unsigned short* __restrict__ qs, unsigned short* __restrict__ kb,
    unsigned short* __restrict__ vt) {
    __shared__ unsigned short lA[2][32 * 64];
    __shared__ unsigned short lB[2][128 * 64];

    const int y = blockIdx.y;
    const float* X = y == 0 ? Qg : (y == 1 ? Kg : Vg);
    const unsigned short* Wt = y == 0 ? Wqt : (y == 1 ? Wkt : Wvt);
    const float* bias = y == 0 ? bq : (y == 1 ? bk : bv);
    // q scale: 1/sqrt(dk) = 1/8, plus fold the tanh 2x -> 0.25
    const float scal = y == 0 ? 0.25f : 1.0f;
    const int row0 = blockIdx.x * 32;
    const int tid = threadIdx.x, lane = tid & 63, wv = tid >> 6;
    const int l16 = lane & 15, lq4 = lane >> 4;
    const int wc = wv;                               // 4 waves = 4 x 32 N-cols

    f32x4 acc[2][2];
    #pragma unroll
    for (int i = 0; i < 2; ++i)
        #pragma unroll
        for (int j = 0; j < 2; ++j) acc[i][j] = f32x4{0.f, 0.f, 0.f, 0.f};

    const int arow = tid >> 3, ac0 = (tid & 7) * 8;
    const int aslot = (tid & 7) ^ (arow & 7);
    const float* xsrc = X + (size_t)(row0 + arow) * DM + ac0;

    float4 x0 = *(const float4*)xsrc;
    float4 x1 = *(const float4*)(xsrc + 4);
    {   // stage W(0) -> lB[0]
        #pragma unroll
        for (int c = 0; c < 4; ++c) {
            int chunk = wv * 4 + c;
            int n = chunk * 8 + (lane >> 3);
            int gslot = (lane & 7) ^ (n & 7);
            async16((const char*)Wt + ((size_t)n * DM) * 2 + gslot * 16,
                    (char*)lB[0] + chunk * 1024 + lane * 16);
        }
    }
    float4 y0 = *(const float4*)(xsrc + 64);
    float4 y1 = *(const float4*)(xsrc + 68);
    {   // write A(0) -> lA[0]
        unsigned* d = (unsigned*)((char*)lA[0] + arow * 128 + aslot * 16);
        d[0] = pk2(x0.x, x0.y); d[1] = pk2(x0.z, x0.w);
        d[2] = pk2(x1.x, x1.y); d[3] = pk2(x1.z, x1.w);
    }
    __syncthreads();

    for (int kc = 0; kc < 8; ++kc) {
        const int cur = kc & 1, nxt = cur ^ 1;
        if (kc < 7) {   // stage W(kc+1) -> lB[nxt]
            #pragma unroll
            for (int c = 0; c < 4; ++c) {
                int chunk = wv * 4 + c;
                int n = chunk * 8 + (lane >> 3);
                int gslot = (lane & 7) ^ (n & 7);
                async16((const char*)Wt + ((size_t)n * DM + (kc + 1) * 64) * 2 + gslot * 16,
                        (char*)lB[nxt] + chunk * 1024 + lane * 16);
            }
        }
        #pragma unroll
        for (int ks = 0; ks < 2; ++ks) {
            short8 a[2], b[2];
            #pragma unroll
            for (int mt = 0; mt < 2; ++mt) {
                int m = mt * 16 + l16;
                unsigned ao = (unsigned)(m * 128 + ks * 64 + lq4 * 16) ^ ((unsigned)(m & 7) << 4);
                a[mt] = *(const short8*)((const char*)lA[cur] + ao);
            }
            #pragma unroll
            for (int nt = 0; nt < 2; ++nt) {
                int n = wc * 32 + nt * 16 + l16;
                unsigned bo2 = (unsigned)(n * 128 + ks * 64 + lq4 * 16) ^ ((unsigned)(n & 7) << 4);
                b[nt] = *(const short8*)((const char*)lB[cur] + bo2);
            }
            #pragma unroll
            for (int mt = 0; mt < 2; ++mt)
                #pragma unroll
                for (int nt = 0; nt < 2; ++nt)
                    acc[mt][nt] = __builtin_amdgcn_mfma_f32_16x16x32_bf16(
                        a[mt], b[nt], acc[mt][nt], 0, 0, 0);
        }
        if (kc < 7) {
            unsigned* d = (unsigned*)((char*)lA[nxt] + arow * 128 + aslot * 16);
            d[0] = pk2(y0.x, y0.y); d[1] = pk2(y0.z, y0.w);
            d[2] = pk2(y1.x, y1.y); d[3] = pk2(y1.z, y1.w);
            if (kc < 6) {
                y0 = *(const float4*)(xsrc + (kc + 2) * 64);
                y1 = *(const float4*)(xsrc + (kc + 2) * 64 + 4);
            }
        }
        __syncthreads();
    }

    if (y < 2) {
        unsigned short* dstp = (y == 0) ? qs : kb;
        #pragma unroll
        for (int mt = 0; mt < 2; ++mt)
            #pragma unroll
            for (int nt = 0; nt < 2; ++nt) {
                int col = wc * 32 + nt * 16 + l16;
                float bb = bias[col];
                int h = col >> 6, d = col & 63;
                #pragma unroll
                for (int r = 0; r < 4; ++r) {
                    int row = row0 + mt * 16 + lq4 * 4 + r;
                    int b = row >> 11, pos = row & 2047;
                    float val = (acc[mt][nt][r] + bb) * scal;
                    dstp[((size_t)(b * NH + h) * SEQ + pos) * DKV + d] = f2bf(val);
                }
            }
    } else {
        #pragma unroll
        for (int mt = 0; mt < 2; ++mt)
            #pragma unroll
            for (int nt = 0; nt < 2; ++nt) {
                int col = wc * 32 + nt * 16 + l16;
                float bb = bias[col];
                #pragma unroll
                for (int r = 0; r < 4; ++r) {
                    int mrow = mt * 16 + lq4 * 4 + r;
                    lB[0][col * 32 + mrow] = f2bf(acc[mt][nt][r] + bb);
                }
            }
        __syncthreads();
        int c = tid >> 1, mp = (tid & 1) * 16;
        int b = row0 >> 11, kpos0 = row0 & 2047;
        int h = c >> 6, d = c & 63;
        unsigned short* dst = vt + ((size_t)(b * NH + h) * DKV + d) * SEQ + kpos0 + mp;
        const unsigned short* srcl = &lB[0][c * 32 + mp];
        *(uint4*)dst = *(const uint4*)srcl;
        *(uint4*)(dst + 8) = *(const uint4*)(srcl + 8);
    }
}

// ---------------------------------------------------------------------------
// k_vsum: Vsum[bh][d] = sum_k vt[bh][d][k]   (for out = S@V - L*Vsum)
__global__ __launch_bounds__(512) void k_vsum(const unsigned short* __restrict__ vt,
                                              float* __restrict__ vs) {
    int bh = blockIdx.x, tid = threadIdx.x;
    int d = tid >> 3, oct = tid & 7;
    const unsigned short* src = vt + ((size_t)bh * DKV + d) * SEQ + oct * 256;
    float s = 0.f;
    #pragma unroll 4
    for (int i = 0; i < 32; ++i) {
        short8 v = *(const short8*)(src + i * 8);
        #pragma unroll
        for (int t = 0; t < 8; ++t) s += bf2f((unsigned short)v[t]);
    }
    s += __shfl_xor(s, 1); s += __shfl_xor(s, 2); s += __shfl_xor(s, 4);
    if (oct == 0) vs[bh * DKV + d] = s;
}

// ---------------------------------------------------------------------------
// k_qk: per (bh, 16-row q-tile): scores s = masked 10*tanh(qk/8) for all 2048
// k-cols -> raw bf16 to global sg (bulk-coalesced via 64KB swizzled LDS) and
// L = log(sum exp(s)) -> Lg. 8 waves x 256 cols each; ONE barrier.
// grid 1024 = 8 bh * 128 qtiles; bh = wg&7 pins each bh to one XCD's L2.
__global__ __launch_bounds__(512, 4) void k_qk(
    const unsigned short* __restrict__ qs, const unsigned short* __restrict__ kb,
    const int* __restrict__ maskg, unsigned short* __restrict__ sg,
    float* __restrict__ Lg) {
    __shared__ unsigned short sS[16 * 2048];      // 64 KB, byte ^= (row&7)<<4
    __shared__ float lsum[8][16];

    const int wg = blockIdx.x;
    const int bh = wg & 7;
    const int qt = wg >> 3;
    const int qbase = qt * 16;
    const int b = bh >> 1;
    const int tid = threadIdx.x, lane = tid & 63, wv = tid >> 6;  // 8 waves
    const int l16 = lane & 15, lq4 = lane >> 4;

    // Q fragments: A rows = qbase + l16 (q pre-scaled by 2/sqrt(dk))
    const unsigned short* qrow =
        qs + ((size_t)bh * SEQ + qbase + l16) * DKV + lq4 * 8;
    short8 aq0 = *(const short8*)qrow;
    short8 aq1 = *(const short8*)(qrow + 32);

    const unsigned short* kf =
        kb + ((size_t)bh * SEQ + wv * 256 + l16) * DKV + lq4 * 8;
    const int* mrow = maskg + b * SEQ + wv * 256 + l16;

    float sums[4] = {0.f, 0.f, 0.f, 0.f};

    short8 b0 = *(const short8*)kf;
    short8 b1 = *(const short8*)(kf + 32);
    int mv = mrow[0];
    for (int kt = 0; kt < 16; ++kt) {
        int nx = (kt + 1) & 15;                   // wrap avoids OOB
        short8 nb0 = *(const short8*)(kf + nx * 1024);
        short8 nb1 = *(const short8*)(kf + nx * 1024 + 32);
        int nmv = mrow[nx * 16];
        f32x4 acc = f32x4{0.f, 0.f, 0.f, 0.f};
        acc = __builtin_amdgcn_mfma_f32_16x16x32_bf16(aq0, b0, acc, 0, 0, 0);
        acc = __builtin_amdgcn_mfma_f32_16x16x32_bf16(aq1, b1, acc, 0, 0, 0);
        int col = wv * 256 + kt * 16 + l16;
        #pragma unroll
        for (int r = 0; r < 4; ++r) {
            float x = acc[r];                     // = 2 * q.k/8
            float e2 = __expf(x);
            float s10 = 10.f - 20.f * __builtin_amdgcn_rcpf(1.f + e2);
            float s = mv ? -10.f : s10;
            sums[r] += __expf(s);
            int row = lq4 * 4 + r;
            unsigned bo = (unsigned)(row * 4096 + col * 2) ^ ((unsigned)(row & 7) << 4);
            *(unsigned short*)((char*)sS + bo) = f2bf(s);
        }
        b0 = nb0; b1 = nb1; mv = nmv;
    }

    #pragma unroll
    for (int r = 0; r < 4; ++r) {
        float v = sums[r];
        v += __shfl_xor(v, 1); v += __shfl_xor(v, 2);
        v += __shfl_xor(v, 4); v += __shfl_xor(v, 8);
        if (l16 == 0) lsum[wv][lq4 * 4 + r] = v;
    }
    __syncthreads();

    if (tid < 16) {
        float t = lsum[0][tid] + lsum[1][tid] + lsum[2][tid] + lsum[3][tid] +
                  lsum[4][tid] + lsum[5][tid] + lsum[6][tid] + lsum[7][tid];
        Lg[(size_t)bh * SEQ + qbase + tid] = __logf(t);
    }

    // bulk store: 16 rows x 4KB, fully coalesced (512B per 32-lane row-group)
    {
        const int row = tid >> 5, t32 = tid & 31;
        unsigned short* gdst = sg + ((size_t)bh * SEQ + qbase + row) * SEQ;
        const unsigned rxor = (unsigned)(row & 7) << 4;
        const unsigned rbase = (unsigned)(row * 4096);
        #pragma unroll
        for (int j = 0; j < 8; ++j) {
            unsigned off = (unsigned)(t32 * 16 + j * 512);
            short8 v = *(const short8*)((const char*)sS + ((rbase + off) ^ rxor));
            *(short8*)((char*)gdst + off) = v;
        }
    }
}

// ---------------------------------------------------------------------------
// k_pvfin: per (bh, 16-row q-tile), NO LDS, NO barriers.
//   PV: out = S @ V - L*Vsum (raw bf16 scores from sg, L3-resident; V from L2)
//   fin: attn = bf2f(s) - L -> global f32 (134MB, coalesced), drains under
//        other blocks' MFMAs. 4 waves = 4 d-groups.
__global__ __launch_bounds__(256, 4) void k_pvfin(
    const unsigned short* __restrict__ sg, const unsigned short* __restrict__ vt,
    const float* __restrict__ Lg, const float* __restrict__ vsumG,
    float* __restrict__ attnG, unsigned short* __restrict__ outh) {
    const int wg = blockIdx.x;
    const int bh = wg & 7;
    const int qt = wg >> 3;
    const int qbase = qt * 16;
    const int b = bh >> 1, h = bh & 1;
    const int tid = threadIdx.x, lane = tid & 63, dg = tid >> 6;
    const int l16 = lane & 15, lq4 = lane >> 4;

    const unsigned short* aptr =
        sg + ((size_t)bh * SEQ + qbase + l16) * SEQ + lq4 * 8;
    const unsigned short* vptr =
        vt + ((size_t)bh * DKV + dg * 16 + l16) * SEQ + lq4 * 8;

    f32x4 o = f32x4{0.f, 0.f, 0.f, 0.f};
    short8 af = *(const short8*)aptr;
    short8 vf = *(const short8*)vptr;
    for (int ks = 0; ks < 64; ++ks) {
        int nk = (ks + 1) & 63;
        short8 naf = *(const short8*)(aptr + nk * 32);
        short8 nvf = *(const short8*)(vptr + nk * 32);
        o = __builtin_amdgcn_mfma_f32_16x16x32_bf16(af, vf, o, 0, 0, 0);
        af = naf; vf = nvf;
    }
    {
        const float vs = vsumG[bh * DKV + dg * 16 + l16];
        #pragma unroll
        for (int r = 0; r < 4; ++r) {
            int qr = qbase + lq4 * 4 + r;
            float Lv = Lg[(size_t)bh * SEQ + qr];
            float val = o[r] - Lv * vs;
            outh[((size_t)b * SEQ + qr) * HDIM + h * DKV + dg * 16 + l16] = f2bf(val);
        }
    }

    // fin: stream attn = s - L. 16 rows x 16 segs; 512B coalesced segments.
    {
        const int row = tid >> 4, seg = tid & 15;
        const unsigned short* srow = sg + ((size_t)bh * SEQ + qbase + row) * SEQ;
        const float Lv = Lg[(size_t)bh * SEQ + qbase + row];
        float* gdst = attnG + ((size_t)bh * SEQ + qbase + row) * SEQ;
        #pragma unroll
        for (int j = 0; j < 16; ++j) {
            int c = j * 128 + seg * 8;
            short8 v = *(const short8*)(srow + c);
            float4 fa, fb;
            fa.x = bf2f((unsigned short)v[0]) - Lv;
            fa.y = bf2f((unsigned short)v[1]) - Lv;
            fa.z = bf2f((unsigned short)v[2]) - Lv;
            fa.w = bf2f((unsigned short)v[3]) - Lv;
            fb.x = bf2f((unsigned short)v[4]) - Lv;
            fb.y = bf2f((unsigned short)v[5]) - Lv;
            fb.z = bf2f((unsigned short)v[6]) - Lv;
            fb.w = bf2f((unsigned short)v[7]) - Lv;
            *(float4*)(gdst + c) = fa;
            *(float4*)(gdst + c + 4) = fb;
        }
    }
}

// ---------------------------------------------------------------------------
// k_oproj: out = outh[8192,128] @ Wo[128,512] + bo.  grid (64, 4).
// Staging pre-swizzled at the global source; reads swizzled -> conflict-free.
__global__ __launch_bounds__(256) void k_oproj(
    const unsigned short* __restrict__ outh, const unsigned short* __restrict__ Wot,
    const float* __restrict__ bo, float* __restrict__ outG) {
    __shared__ unsigned short lA2[128 * 128];
    __shared__ unsigned short lB2[128 * 128];
    const int row0 = blockIdx.x * 128, col0 = blockIdx.y * 128;
    const int tid = threadIdx.x, lane = tid & 63, wv = tid >> 6;
    const int l16 = lane & 15, lq4 = lane >> 4;
    const int wr = wv >> 1, wc = wv & 1;

    #pragma unroll
    for (int c = 0; c < 8; ++c) {
        int chunk = wv * 8 + c;
        int row = chunk * 4 + (lane >> 4);
        int gslot = (lane & 15) ^ (row & 7);
        async16((const char*)outh + ((size_t)(row0 + row)) * 256 + gslot * 16,
                (char*)lA2 + chunk * 1024 + lane * 16);
    }
    #pragma unroll
    for (int c = 0; c < 8; ++c) {
        int chunk = wv * 8 + c;
        int row = chunk * 4 + (lane >> 4);
        int gslot = (lane & 15) ^ (row & 7);
        async16((const char*)Wot + ((size_t)(col0 + row)) * 256 + gslot * 16,
                (char*)lB2 + chunk * 1024 + lane * 16);
    }
    __syncthreads();

    f32x4 acc[4][4];
    #pragma unroll
    for (int mt = 0; mt < 4; ++mt)
        #pragma unroll
        for (int nt = 0; nt < 4; ++nt) acc[mt][nt] = f32x4{0.f, 0.f, 0.f, 0.f};

    #pragma unroll
    for (int ks = 0; ks < 4; ++ks) {
        short8 a[4], bfr[4];
        #pragma unroll
        for (int mt = 0; mt < 4; ++mt) {
            int m = wr * 64 + mt * 16 + l16;
            unsigned ao = (unsigned)(m * 256 + ks * 64 + lq4 * 16) ^ ((unsigned)(m & 7) << 4);
            a[mt] = *(const short8*)((const char*)lA2 + ao);
        }
        #pragma unroll
        for (int nt = 0; nt < 4; ++nt) {
            int n = wc * 64 + nt * 16 + l16;
            unsigned bo2 = (unsigned)(n * 256 + ks * 64 + lq4 * 16) ^ ((unsigned)(n & 7) << 4);
            bfr[nt] = *(const short8*)((const char*)lB2 + bo2);
        }
        #pragma unroll
        for (int mt = 0; mt < 4; ++mt)
            #pragma unroll
            for (int nt = 0; nt < 4; ++nt)
                acc[mt][nt] = __builtin_amdgcn_mfma_f32_16x16x32_bf16(
                    a[mt], bfr[nt], acc[mt][nt], 0, 0, 0);
    }

    #pragma unroll
    for (int nt = 0; nt < 4; ++nt) {
        int col = col0 + wc * 64 + nt * 16 + l16;
        float bb = bo[col];
        #pragma unroll
        for (int mt = 0; mt < 4; ++mt)
            #pragma unroll
            for (int r = 0; r < 4; ++r) {
                int row = row0 + wr * 64 + mt * 16 + lq4 * 4 + r;
                outG[(size_t)row * DM + col] = acc[mt][nt][r] + bb;
            }
    }
}

// ---------------------------------------------------------------------------
extern "C" void kernel_launch(void* const* d_in, const int* in_sizes, int n_in,
                              void* d_out, int out_size, void* d_ws, size_t ws_size,
                              hipStream_t stream) {
    (void)in_sizes; (void)n_in; (void)out_size; (void)ws_size;
    const float* Qg = (const float*)d_in[0];
    const float* Kg = (const float*)d_in[1];
    const float* Vg = (const float*)d_in[2];
    const int*   maskg = (const int*)d_in[3];
    const float* Wq = (const float*)d_in[4];
    const float* bq = (const float*)d_in[5];
    const float* Wk = (const float*)d_in[6];
    const float* bk = (const float*)d_in[7];
    const float* Wv = (const float*)d_in[8];
    const float* bv = (const float*)d_in[9];
    const float* Wo = (const float*)d_in[10];
    const float* bo = (const float*)d_in[11];

    char* ws = (char*)d_ws;
    unsigned short* qs   = (unsigned short*)(ws);                    // 2 MB
    unsigned short* kb   = (unsigned short*)(ws + (4  << 20));       // 2 MB
    unsigned short* vt   = (unsigned short*)(ws + (8  << 20));       // 2 MB
    unsigned short* outh = (unsigned short*)(ws + (28 << 20));       // 2 MB
    float*          vsum = (float*)(ws + (30 << 20));                // 2 KB
    unsigned short* Wqt  = (unsigned short*)(ws + (30 << 20) + 262144);
    unsigned short* Wkt  = (unsigned short*)((char*)Wqt + 131072);
    unsigned short* Wvt  = (unsigned short*)((char*)Wkt + 131072);
    unsigned short* Wot  = (unsigned short*)((char*)Wvt + 131072);
    unsigned short* sg   = (unsigned short*)(ws + ((size_t)32 << 20)); // 64 MB
    float*          Lg   = (float*)(ws + ((size_t)96 << 20));          // 64 KB

    float* outG  = (float*)d_out;
    float* attnG = outG + (size_t)NB * SEQ * DM;

    hipLaunchKernelGGL(k_prep, dim3(1024), dim3(256), 0, stream,
                       Wq, Wk, Wv, Wo, Wqt, Wkt, Wvt, Wot);
    hipLaunchKernelGGL(k_proj, dim3(256, 3), dim3(256), 0, stream,
                       Qg, Kg, Vg, Wqt, Wkt, Wvt, bq, bk, bv, qs, kb, vt);
    hipLaunchKernelGGL(k_vsum, dim3(8), dim3(512), 0, stream, vt, vsum);
    hipLaunchKernelGGL(k_qk, dim3(1024), dim3(512), 0, stream,
                       qs, kb, maskg, sg, Lg);
    hipLaunchKernelGGL(k_pvfin, dim3(1024), dim3(256), 0, stream,
                       sg, vt, Lg, vsum, attnG, outh);
    hipLaunchKernelGGL(k_oproj, dim3(64, 4), dim3(256), 0, stream, outh, Wot, bo, outG);
}

// Round 4
// 259.293 us; speedup vs baseline: 1.2646x; 1.2646x over previous
//
#include <hip/hip_runtime.h>

typedef __attribute__((ext_vector_type(8))) short short8;
typedef __attribute__((ext_vector_type(4))) short short4v;
typedef __attribute__((ext_vector_type(4))) float f32x4;

#define DEVI static __device__ __forceinline__

constexpr int NB   = 4;     // batch
constexpr int NH   = 2;     // heads
constexpr int SEQ  = 2048;  // Lq = Lk
constexpr int DM   = 512;   // d_model
constexpr int DKV  = 64;    // d_k = d_v
constexpr int HDIM = 128;   // NH * DKV

DEVI unsigned short f2bf(float f) {
    union { float f; unsigned u; } v; v.f = f;
    unsigned r = v.u + 0x7FFFu + ((v.u >> 16) & 1u);
    return (unsigned short)(r >> 16);
}
DEVI float bf2f(unsigned short s) {
    union { unsigned u; float f; } v; v.u = ((unsigned)s) << 16; return v.f;
}
DEVI unsigned pk2(float a, float b) {
    return (unsigned)f2bf(a) | ((unsigned)f2bf(b) << 16);
}
// async global->LDS, 16B per lane. LDS dest = wave-uniform base + lane*16.
DEVI void async16(const void* g, void* l) {
    __builtin_amdgcn_global_load_lds(
        (const __attribute__((address_space(1))) unsigned int*)g,
        (__attribute__((address_space(3))) unsigned int*)l, 16, 0, 0);
}

// ---------------------------------------------------------------------------
// k_prep: weights f32 -> bf16 transposed, via LDS tile transpose.
// Coalesced f32 reads (was 512B-strided scalar: ~32x fetch amplification) and
// coalesced 32B bf16 writes. 64 blocks: 48 for Wq/Wk/Wv, 16 for Wo.
__global__ __launch_bounds__(256) void k_prep(
    const float* __restrict__ Wq, const float* __restrict__ Wk,
    const float* __restrict__ Wv, const float* __restrict__ Wo,
    unsigned short* __restrict__ Wqt, unsigned short* __restrict__ Wkt,
    unsigned short* __restrict__ Wvt, unsigned short* __restrict__ Wot) {
    __shared__ unsigned short T[64][72];          // +8 pad
    const int bid = blockIdx.x, tid = threadIdx.x;
    const float* src; unsigned short* dst; int ss, ds, k0, n0;
    if (bid < 48) {                               // W[512k][128n] -> Wt[128n][512k]
        int m = bid >> 4, t16 = bid & 15;
        src = m == 0 ? Wq : (m == 1 ? Wk : Wv);
        dst = m == 0 ? Wqt : (m == 1 ? Wkt : Wvt);
        ss = 128; ds = 512;
        k0 = (t16 >> 1) * 64; n0 = (t16 & 1) * 64;
    } else {                                      // Wo[128k][512n] -> Wot[512n][128k]
        int t16 = bid - 48;
        src = Wo; dst = Wot; ss = 512; ds = 128;
        k0 = (t16 >> 3) * 64; n0 = (t16 & 7) * 64;
    }
    const int kk = tid >> 4, nn4 = (tid & 15) * 4;
    #pragma unroll
    for (int i = 0; i < 4; ++i) {
        float4 v = *(const float4*)(src + (size_t)(k0 + kk + i * 16) * ss + n0 + nn4);
        T[kk + i * 16][nn4]     = f2bf(v.x);
        T[kk + i * 16][nn4 + 1] = f2bf(v.y);
        T[kk + i * 16][nn4 + 2] = f2bf(v.z);
        T[kk + i * 16][nn4 + 3] = f2bf(v.w);
    }
    __syncthreads();
    const int nn = tid >> 2, kc = (tid & 3) * 16;
    unsigned short tmp[16];
    #pragma unroll
    for (int i = 0; i < 16; ++i) tmp[i] = T[kc + i][nn];
    unsigned short* o = dst + (size_t)(n0 + nn) * ds + k0 + kc;
    *(uint4*)o       = *(uint4*)tmp;
    *(uint4*)(o + 8) = *(uint4*)(tmp + 8);
}

// ---------------------------------------------------------------------------
// k_proj: X[8192,512] @ W[512,128] + b  ->  per-head bf16 layouts.
// (round-0 proven version, verbatim)
__global__ __launch_bounds__(256) void k_proj(
    const float* __restrict__ Qg, const float* __restrict__ Kg, const float* __restrict__ Vg,
    const unsigned short* __restrict__ Wqt, const unsigned short* __restrict__ Wkt,
    const unsigned short* __restrict__ Wvt,
    const float* __restrict__ bq, const float* __restrict__ bk, const float* __restrict__ bv,
    unsigned short* __restrict__ qs, unsigned short* __restrict__ kb,
    unsigned short* __restrict__ vt) {
    __shared__ unsigned short lA[64 * 64];
    __shared__ unsigned short lB[128 * 64];

    const int y = blockIdx.y;
    const float* X = y == 0 ? Qg : (y == 1 ? Kg : Vg);
    const unsigned short* Wt = y == 0 ? Wqt : (y == 1 ? Wkt : Wvt);
    const float* bias = y == 0 ? bq : (y == 1 ? bk : bv);
    const float scal = y == 0 ? 0.125f : 1.0f;   // fold 1/sqrt(dk) into q
    const int row0 = blockIdx.x * 64;
    const int tid = threadIdx.x, lane = tid & 63, wv = tid >> 6;
    const int l16 = lane & 15, lq4 = lane >> 4;
    const int wr = wv >> 1, wc = wv & 1;

    f32x4 acc[2][4];
    #pragma unroll
    for (int i = 0; i < 2; ++i)
        #pragma unroll
        for (int j = 0; j < 4; ++j) acc[i][j] = f32x4{0.f, 0.f, 0.f, 0.f};

    const int arow = tid >> 2, ac0 = (tid & 3) * 16;

    for (int kc = 0; kc < 8; ++kc) {
        {
            const float* src = X + (size_t)(row0 + arow) * DM + kc * 64 + ac0;
            unsigned short* dst = &lA[arow * 64 + ac0];
            #pragma unroll
            for (int i = 0; i < 4; ++i) {
                float4 v = *(const float4*)(src + 4 * i);
                unsigned p0 = (unsigned)f2bf(v.x) | ((unsigned)f2bf(v.y) << 16);
                unsigned p1 = (unsigned)f2bf(v.z) | ((unsigned)f2bf(v.w) << 16);
                *(unsigned*)(dst + 4 * i) = p0;
                *(unsigned*)(dst + 4 * i + 2) = p1;
            }
        }
        #pragma unroll
        for (int c = 0; c < 4; ++c) {
            int chunk = wv * 4 + c;
            int n = chunk * 8 + (lane >> 3);
            int kpart = (lane & 7) * 8;
            const void* g = (const char*)Wt + ((size_t)n * DM + kc * 64 + kpart) * 2;
            void* l = (char*)lB + chunk * 1024 + lane * 16;
            async16(g, l);
        }
        __syncthreads();

        #pragma unroll
        for (int ks = 0; ks < 2; ++ks) {
            short8 a[2], b[4];
            #pragma unroll
            for (int mt = 0; mt < 2; ++mt) {
                int m = wr * 32 + mt * 16 + l16;
                a[mt] = *(const short8*)&lA[m * 64 + ks * 32 + lq4 * 8];
            }
            #pragma unroll
            for (int nt = 0; nt < 4; ++nt) {
                int n = wc * 64 + nt * 16 + l16;
                b[nt] = *(const short8*)&lB[n * 64 + ks * 32 + lq4 * 8];
            }
            #pragma unroll
            for (int mt = 0; mt < 2; ++mt)
                #pragma unroll
                for (int nt = 0; nt < 4; ++nt)
                    acc[mt][nt] = __builtin_amdgcn_mfma_f32_16x16x32_bf16(
                        a[mt], b[nt], acc[mt][nt], 0, 0, 0);
        }
        __syncthreads();
    }

    if (y < 2) {
        unsigned short* dstp = (y == 0) ? qs : kb;
        #pragma unroll
        for (int mt = 0; mt < 2; ++mt)
            #pragma unroll
            for (int nt = 0; nt < 4; ++nt) {
                int col = wc * 64 + nt * 16 + l16;
                float bb = bias[col];
                int h = col >> 6, d = col & 63;
                #pragma unroll
                for (int r = 0; r < 4; ++r) {
                    int row = row0 + wr * 32 + mt * 16 + lq4 * 4 + r;
                    int b = row >> 11, pos = row & 2047;
                    float val = (acc[mt][nt][r] + bb) * scal;
                    dstp[((size_t)(b * NH + h) * SEQ + pos) * DKV + d] = f2bf(val);
                }
            }
    } else {
        #pragma unroll
        for (int mt = 0; mt < 2; ++mt)
            #pragma unroll
            for (int nt = 0; nt < 4; ++nt) {
                int col = wc * 64 + nt * 16 + l16;
                float bb = bias[col];
                #pragma unroll
                for (int r = 0; r < 4; ++r) {
                    int mrow = wr * 32 + mt * 16 + lq4 * 4 + r;
                    lB[col * 64 + mrow] = f2bf(acc[mt][nt][r] + bb);
                }
            }
        __syncthreads();
        int c = tid >> 1, mp = (tid & 1) * 32;
        int b = row0 >> 11, kpos0 = row0 & 2047;
        int h = c >> 6, d = c & 63;
        unsigned short* dst = vt + ((size_t)(b * NH + h) * DKV + d) * SEQ + kpos0 + mp;
        const unsigned short* srcl = &lB[c * 64 + mp];
        #pragma unroll
        for (int i = 0; i < 4; ++i)
            *(uint4*)(dst + 8 * i) = *(const uint4*)(srcl + 8 * i);
    }
}

// ---------------------------------------------------------------------------
// k_pass1: per (b,h,64-row q-tile, k-quarter): partial sum_k exp(masked tanh score).
// grid 1024 = 8 bh * 32 q-tiles * 4 k-quarters. (round-0 proven version)
__global__ __launch_bounds__(256) void k_pass1(
    const unsigned short* __restrict__ qs, const unsigned short* __restrict__ kb,
    const int* __restrict__ maskg, float* __restrict__ Lpart) {
    __shared__ unsigned short lK[128 * 64];
    __shared__ int lM[128];
    __shared__ float lsumW[4 * 64];

    const int bx = blockIdx.x;
    const int ksp = bx & 3;
    const int qt = (bx >> 2) & 31;
    const int bh = bx >> 7;
    const int qbase = qt * 64;
    const int b = bh >> 1;
    const int tid = threadIdx.x, lane = tid & 63, wv = tid >> 6;
    const int l16 = lane & 15, lq4 = lane >> 4;

    short8 aq[4][2];
    #pragma unroll
    for (int mt = 0; mt < 4; ++mt)
        #pragma unroll
        for (int ks = 0; ks < 2; ++ks) {
            size_t off = ((size_t)bh * SEQ + qbase + mt * 16 + l16) * DKV + ks * 32 + lq4 * 8;
            aq[mt][ks] = *(const short8*)(qs + off);
        }

    float sums[4][4];
    #pragma unroll
    for (int mt = 0; mt < 4; ++mt)
        #pragma unroll
        for (int r = 0; r < 4; ++r) sums[mt][r] = 0.f;

    const char* kbase_ptr = (const char*)(kb + (size_t)bh * SEQ * DKV);

    for (int kt = ksp * 4; kt < ksp * 4 + 4; ++kt) {
        int kbase = kt * 128;
        #pragma unroll
        for (int c = 0; c < 4; ++c) {
            int chunk = wv * 4 + c;
            const void* g = kbase_ptr + (size_t)kbase * 128 + chunk * 1024 + lane * 16;
            void* l = (char*)lK + chunk * 1024 + lane * 16;
            async16(g, l);
        }
        if (tid < 128) lM[tid] = maskg[b * SEQ + kbase + tid];
        __syncthreads();

        f32x4 acc[4][2];
        #pragma unroll
        for (int mt = 0; mt < 4; ++mt)
            #pragma unroll
            for (int nt = 0; nt < 2; ++nt) acc[mt][nt] = f32x4{0.f, 0.f, 0.f, 0.f};
        #pragma unroll
        for (int ks = 0; ks < 2; ++ks) {
            short8 bfr[2];
            #pragma unroll
            for (int nt = 0; nt < 2; ++nt) {
                int n = wv * 32 + nt * 16 + l16;
                bfr[nt] = *(const short8*)&lK[n * 64 + ks * 32 + lq4 * 8];
            }
            #pragma unroll
            for (int mt = 0; mt < 4; ++mt)
                #pragma unroll
                for (int nt = 0; nt < 2; ++nt)
                    acc[mt][nt] = __builtin_amdgcn_mfma_f32_16x16x32_bf16(
                        aq[mt][ks], bfr[nt], acc[mt][nt], 0, 0, 0);
        }
        #pragma unroll
        for (int nt = 0; nt < 2; ++nt) {
            int col = wv * 32 + nt * 16 + l16;
            int mv = lM[col];
            #pragma unroll
            for (int mt = 0; mt < 4; ++mt)
                #pragma unroll
                for (int r = 0; r < 4; ++r) {
                    float x = acc[mt][nt][r];                      // q.k / 8
                    float e2 = __expf(2.f * x);
                    float s10 = 10.f - 20.f * __builtin_amdgcn_rcpf(1.f + e2);
                    float s = mv ? -10.f : s10;
                    sums[mt][r] += __expf(s);
                }
        }
        __syncthreads();
    }

    #pragma unroll
    for (int mt = 0; mt < 4; ++mt)
        #pragma unroll
        for (int r = 0; r < 4; ++r) {
            float v = sums[mt][r];
            v += __shfl_xor(v, 1); v += __shfl_xor(v, 2);
            v += __shfl_xor(v, 4); v += __shfl_xor(v, 8);
            if (l16 == 0) lsumW[wv * 64 + mt * 16 + lq4 * 4 + r] = v;
        }
    __syncthreads();
    if (tid < 64) {
        float v = lsumW[tid] + lsumW[64 + tid] + lsumW[128 + tid] + lsumW[192 + tid];
        Lpart[(size_t)ksp * (8 * SEQ) + (size_t)bh * SEQ + qbase + tid] = v;
    }
}

// ---------------------------------------------------------------------------
// k_pass2: per (b,h,64-row q-tile, k-quarter):
//   attn = masked tanh score - log(sum Lpart) -> global (f32) ; out_part += attn @ v
// grid 1024 = 8 bh * 32 q-tiles * 4 k-quarters. (round-0 proven version)
__global__ __launch_bounds__(256) void k_pass2(
    const unsigned short* __restrict__ qs, const unsigned short* __restrict__ kb,
    const unsigned short* __restrict__ vt, const int* __restrict__ maskg,
    const float* __restrict__ Lpart, float* __restrict__ attnG, float* __restrict__ outh2) {
    __shared__ unsigned short lK[128 * 64];      // k tile  [kpos][d]
    __shared__ unsigned short lV[64 * 128];      // v^T tile [d][kpos]
    __shared__ unsigned short lAttn[64 * 136];   // attn tile [q][kpos], +8 pad
    __shared__ int lM[128];

    const int bx = blockIdx.x;
    const int ksp = bx & 3;
    const int qt = (bx >> 2) & 31;
    const int bh = bx >> 7;
    const int qbase = qt * 64;
    const int b = bh >> 1, h = bh & 1;
    const int tid = threadIdx.x, lane = tid & 63, wv = tid >> 6;
    const int l16 = lane & 15, lq4 = lane >> 4;

    short8 aq[4][2];
    #pragma unroll
    for (int mt = 0; mt < 4; ++mt)
        #pragma unroll
        for (int ks = 0; ks < 2; ++ks) {
            size_t off = ((size_t)bh * SEQ + qbase + mt * 16 + l16) * DKV + ks * 32 + lq4 * 8;
            aq[mt][ks] = *(const short8*)(qs + off);
        }

    float Lr[4][4];
    #pragma unroll
    for (int mt = 0; mt < 4; ++mt)
        #pragma unroll
        for (int r = 0; r < 4; ++r) {
            size_t idx = (size_t)bh * SEQ + qbase + mt * 16 + lq4 * 4 + r;
            float s = Lpart[idx] + Lpart[8 * SEQ + idx] +
                      Lpart[2 * 8 * SEQ + idx] + Lpart[3 * 8 * SEQ + idx];
            Lr[mt][r] = __logf(s);
        }

    f32x4 o[4];
    #pragma unroll
    for (int mt = 0; mt < 4; ++mt) o[mt] = f32x4{0.f, 0.f, 0.f, 0.f};

    const char* kbase_ptr = (const char*)(kb + (size_t)bh * SEQ * DKV);

    for (int kt = ksp * 4; kt < ksp * 4 + 4; ++kt) {
        int kbase = kt * 128;
        #pragma unroll
        for (int c = 0; c < 4; ++c) {
            int chunk = wv * 4 + c;
            const void* g = kbase_ptr + (size_t)kbase * 128 + chunk * 1024 + lane * 16;
            void* l = (char*)lK + chunk * 1024 + lane * 16;
            async16(g, l);
        }
        #pragma unroll
        for (int c = 0; c < 4; ++c) {
            int chunk = wv * 4 + c;
            int d = chunk * 4 + (lane >> 4);
            int kk = (lane & 15) * 8;
            const void* g = (const char*)vt + (((size_t)bh * DKV + d) * SEQ + kbase + kk) * 2;
            void* l = (char*)lV + chunk * 1024 + lane * 16;
            async16(g, l);
        }
        if (tid < 128) lM[tid] = maskg[b * SEQ + kbase + tid];
        __syncthreads();

        // scores
        f32x4 s[4][2];
        #pragma unroll
        for (int mt = 0; mt < 4; ++mt)
            #pragma unroll
            for (int nt = 0; nt < 2; ++nt) s[mt][nt] = f32x4{0.f, 0.f, 0.f, 0.f};
        #pragma unroll
        for (int ks = 0; ks < 2; ++ks) {
            short8 bfr[2];
            #pragma unroll
            for (int nt = 0; nt < 2; ++nt) {
                int n = wv * 32 + nt * 16 + l16;
                bfr[nt] = *(const short8*)&lK[n * 64 + ks * 32 + lq4 * 8];
            }
            #pragma unroll
            for (int mt = 0; mt < 4; ++mt)
                #pragma unroll
                for (int nt = 0; nt < 2; ++nt)
                    s[mt][nt] = __builtin_amdgcn_mfma_f32_16x16x32_bf16(
                        aq[mt][ks], bfr[nt], s[mt][nt], 0, 0, 0);
        }
        // attn = masked tanh score - L  -> LDS (bf16), C-layout -> row-major
        #pragma unroll
        for (int nt = 0; nt < 2; ++nt) {
            int col = wv * 32 + nt * 16 + l16;
            int mv = lM[col];
            #pragma unroll
            for (int mt = 0; mt < 4; ++mt)
                #pragma unroll
                for (int r = 0; r < 4; ++r) {
                    float x = s[mt][nt][r];
                    float e2 = __expf(2.f * x);
                    float s10 = 10.f - 20.f * __builtin_amdgcn_rcpf(1.f + e2);
                    float a = (mv ? -10.f : s10) - Lr[mt][r];
                    lAttn[(mt * 16 + lq4 * 4 + r) * 136 + col] = f2bf(a);
                }
        }
        __syncthreads();

        // out += attn @ v   (A from lAttn, B from lV)
        #pragma unroll
        for (int ks = 0; ks < 4; ++ks) {
            short8 bfr = *(const short8*)&lV[(wv * 16 + l16) * 128 + ks * 32 + lq4 * 8];
            #pragma unroll
            for (int mt = 0; mt < 4; ++mt) {
                short8 af = *(const short8*)&lAttn[(mt * 16 + l16) * 136 + ks * 32 + lq4 * 8];
                o[mt] = __builtin_amdgcn_mfma_f32_16x16x32_bf16(af, bfr, o[mt], 0, 0, 0);
            }
        }
        // attn tile -> global f32, coalesced
        #pragma unroll
        for (int j = 0; j < 8; ++j) {
            int row = j * 8 + (tid >> 5);
            int col = (tid & 31) * 4;
            short4v hv = *(const short4v*)&lAttn[row * 136 + col];
            float4 f;
            f.x = bf2f((unsigned short)hv[0]); f.y = bf2f((unsigned short)hv[1]);
            f.z = bf2f((unsigned short)hv[2]); f.w = bf2f((unsigned short)hv[3]);
            float* gdst = attnG + ((size_t)bh * SEQ + qbase + row) * SEQ + kbase + col;
            *(float4*)gdst = f;
        }
        __syncthreads();
    }

    // partial out-heads (f32, per k-quarter)
    float* dst = outh2 + (size_t)ksp * (8192 * HDIM);
    #pragma unroll
    for (int mt = 0; mt < 4; ++mt)
        #pragma unroll
        for (int r = 0; r < 4; ++r) {
            int q = qbase + mt * 16 + lq4 * 4 + r;
            int dcol = wv * 16 + l16;
            dst[((size_t)b * SEQ + q) * HDIM + h * DKV + dcol] = o[mt][r];
        }
}

// ---------------------------------------------------------------------------
// k_oproj (+comb fused): out = (sum of 4 outh2 partials)[8192,128] @ Wo + bo.
// A staged by reading the 4 f32 partials coalesced, summed+packed to bf16 in
// registers, swizzled ds_write. B via pre-swizzled async16 of Wot. grid (64,4).
__global__ __launch_bounds__(256) void k_oproj(
    const float* __restrict__ outh2, const unsigned short* __restrict__ Wot,
    const float* __restrict__ bo, float* __restrict__ outG) {
    __shared__ unsigned short lA2[128 * 128];
    __shared__ unsigned short lB2[128 * 128];
    const int row0 = blockIdx.x * 128, col0 = blockIdx.y * 128;
    const int tid = threadIdx.x, lane = tid & 63, wv = tid >> 6;
    const int l16 = lane & 15, lq4 = lane >> 4;
    const int wr = wv >> 1, wc = wv & 1;

    #pragma unroll
    for (int c = 0; c < 8; ++c) {
        int chunk = wv * 8 + c;
        int row = chunk * 4 + (lane >> 4);
        int gslot = (lane & 15) ^ (row & 7);
        async16((const char*)Wot + ((size_t)(col0 + row)) * 256 + gslot * 16,
                (char*)lB2 + chunk * 1024 + lane * 16);
    }
    {   // A: sum 4 partials, f32 -> bf16, swizzled 8B LDS writes
        const int c16 = tid & 31;                 // 16B f32 chunk (4 cols)
        const int rb = tid >> 5;                  // row 0..7, step 8
        #pragma unroll
        for (int i = 0; i < 16; ++i) {
            int r = rb + i * 8;
            size_t off = (size_t)(row0 + r) * 128 + c16 * 4;
            float4 a = *(const float4*)(outh2 + off);
            float4 b = *(const float4*)(outh2 + 1048576 + off);
            float4 c = *(const float4*)(outh2 + 2 * 1048576 + off);
            float4 d = *(const float4*)(outh2 + 3 * 1048576 + off);
            unsigned p0 = pk2(a.x + b.x + c.x + d.x, a.y + b.y + c.y + d.y);
            unsigned p1 = pk2(a.z + b.z + c.z + d.z, a.w + b.w + c.w + d.w);
            unsigned long long pk =
                (unsigned long long)p0 | ((unsigned long long)p1 << 32);
            unsigned bo2 = (unsigned)(r * 256 + c16 * 8) ^ ((unsigned)(r & 7) << 4);
            *(unsigned long long*)((char*)lA2 + bo2) = pk;
        }
    }
    __syncthreads();

    f32x4 acc[4][4];
    #pragma unroll
    for (int mt = 0; mt < 4; ++mt)
        #pragma unroll
        for (int nt = 0; nt < 4; ++nt) acc[mt][nt] = f32x4{0.f, 0.f, 0.f, 0.f};

    #pragma unroll
    for (int ks = 0; ks < 4; ++ks) {
        short8 a[4], bfr[4];
        #pragma unroll
        for (int mt = 0; mt < 4; ++mt) {
            int m = wr * 64 + mt * 16 + l16;
            unsigned ao = (unsigned)(m * 256 + ks * 64 + lq4 * 16) ^ ((unsigned)(m & 7) << 4);
            a[mt] = *(const short8*)((const char*)lA2 + ao);
        }
        #pragma unroll
        for (int nt = 0; nt < 4; ++nt) {
            int n = wc * 64 + nt * 16 + l16;
            unsigned bo2 = (unsigned)(n * 256 + ks * 64 + lq4 * 16) ^ ((unsigned)(n & 7) << 4);
            bfr[nt] = *(const short8*)((const char*)lB2 + bo2);
        }
        #pragma unroll
        for (int mt = 0; mt < 4; ++mt)
            #pragma unroll
            for (int nt = 0; nt < 4; ++nt)
                acc[mt][nt] = __builtin_amdgcn_mfma_f32_16x16x32_bf16(
                    a[mt], bfr[nt], acc[mt][nt], 0, 0, 0);
    }

    #pragma unroll
    for (int nt = 0; nt < 4; ++nt) {
        int col = col0 + wc * 64 + nt * 16 + l16;
        float bb = bo[col];
        #pragma unroll
        for (int mt = 0; mt < 4; ++mt)
            #pragma unroll
            for (int r = 0; r < 4; ++r) {
                int row = row0 + wr * 64 + mt * 16 + lq4 * 4 + r;
                outG[(size_t)row * DM + col] = acc[mt][nt][r] + bb;
            }
    }
}

// ---------------------------------------------------------------------------
extern "C" void kernel_launch(void* const* d_in, const int* in_sizes, int n_in,
                              void* d_out, int out_size, void* d_ws, size_t ws_size,
                              hipStream_t stream) {
    (void)in_sizes; (void)n_in; (void)out_size; (void)ws_size;
    const float* Qg = (const float*)d_in[0];
    const float* Kg = (const float*)d_in[1];
    const float* Vg = (const float*)d_in[2];
    const int*   maskg = (const int*)d_in[3];
    const float* Wq = (const float*)d_in[4];
    const float* bq = (const float*)d_in[5];
    const float* Wk = (const float*)d_in[6];
    const float* bk = (const float*)d_in[7];
    const float* Wv = (const float*)d_in[8];
    const float* bv = (const float*)d_in[9];
    const float* Wo = (const float*)d_in[10];
    const float* bo = (const float*)d_in[11];

    char* ws = (char*)d_ws;
    unsigned short* qs   = (unsigned short*)(ws);                    // 2 MB
    unsigned short* kb   = (unsigned short*)(ws + (4  << 20));       // 2 MB
    unsigned short* vt   = (unsigned short*)(ws + (8  << 20));       // 2 MB
    float*          outh2= (float*)(ws + (12 << 20));                // 16 MB (4 quarters)
    float*          Lpart= (float*)(ws + (30 << 20));                // 256 KB
    unsigned short* Wqt  = (unsigned short*)(ws + (30 << 20) + 262144);
    unsigned short* Wkt  = (unsigned short*)((char*)Wqt + 131072);
    unsigned short* Wvt  = (unsigned short*)((char*)Wkt + 131072);
    unsigned short* Wot  = (unsigned short*)((char*)Wvt + 131072);

    float* outG  = (float*)d_out;
    float* attnG = outG + (size_t)NB * SEQ * DM;

    hipLaunchKernelGGL(k_prep, dim3(64), dim3(256), 0, stream,
                       Wq, Wk, Wv, Wo, Wqt, Wkt, Wvt, Wot);
    hipLaunchKernelGGL(k_proj, dim3(128, 3), dim3(256), 0, stream,
                       Qg, Kg, Vg, Wqt, Wkt, Wvt, bq, bk, bv, qs, kb, vt);
    hipLaunchKernelGGL(k_pass1, dim3(1024), dim3(256), 0, stream, qs, kb, maskg, Lpart);
    hipLaunchKernelGGL(k_pass2, dim3(1024), dim3(256), 0, stream,
                       qs, kb, vt, maskg, Lpart, attnG, outh2);
    hipLaunchKernelGGL(k_oproj, dim3(64, 4), dim3(256), 0, stream, outh2, Wot, bo, outG);
}